// Round 6
// baseline (163.093 us; speedup 1.0000x reference)
//
#include <hip/hip_runtime.h>

// SNN forward, fused single-pass, VALU-minimized.
//
// spike(h) = (h >= 2.0f)   (h/TAU >= 1 <=> h >= 2, exact in IEEE)
//
// R5: two VALU cuts on the R4 structure (which was VALU-issue-bound:
// 52-54us invariant to occupancy 21%->41%, HBM only 24%):
//  1. gmax bound: h2_j <= popc(m1)*max(W2) -- if popc*gmax < 1.99f the row
//     provably can't fire layer 2 (even with FP rounding: k<=32, error
//     < 3eps relative) -> skip the whole sparse body. Only ~0.6% of rows
//     have popc>=4, so ~68% of WAVES skip entirely (vs 100% executing it).
//  2. packed f32: both rows of a thread as float2 -> v_pk_fma_f32 halves
//     L1 fma issue. Same expression form as R0-R4 (absmax 0.0 x4) so
//     contraction/rounding per component is unchanged.
// Outputs: LDS out region bulk-zeroed with b128 writes; only rare m2!=0
// rows write o (5x ds_write_b64). Coalesced NT float4 flush.

typedef float v2f __attribute__((ext_vector_type(2)));
typedef float v4f __attribute__((ext_vector_type(4)));

#define RPB 512   // rows per block (256 threads x 2 rows)

__global__ __launch_bounds__(256) void snn_fused(
    const float* __restrict__ x,
    const float* __restrict__ W1,   // [32,5]
    const float* __restrict__ W2,   // [32,32]
    const float* __restrict__ W3,   // [16,32]
    const float* __restrict__ W4,   // [10,16]
    float* __restrict__ out,        // [B,10]
    int B)
{
    __shared__ __align__(16) float buf[RPB * 10];  // 20KB: x-stage / out union
    __shared__ float w2t[32 * 36];                 // W2^T, 144B rows
    __shared__ unsigned s_gmax;

    const int t = threadIdx.x;
    const long base = (long)blockIdx.x * RPB;
    const int nrows = (int)min((long)RPB, (long)B - base);

    if (t == 0) s_gmax = 0u;
    __syncthreads();

    // ---- stage W2^T, tracking max positive entry ----
    float lmax = 0.0f;
#pragma unroll
    for (int e = t; e < 1024; e += 256) {
        int j = e >> 5, i = e & 31;
        float w = W2[e];
        w2t[i * 36 + j] = w;
        lmax = fmaxf(lmax, w);
    }
    if (lmax > 0.0f) atomicMax(&s_gmax, __float_as_uint(lmax));  // positive floats: uint order == float order

    // ---- coalesced x stage ----
    if (nrows == RPB) {
        const v4f* xg = (const v4f*)(x + base * 5);
        v4f* b4 = (v4f*)buf;
#pragma unroll
        for (int e = 0; e < 3; ++e) {
            int idx = e * 256 + t;
            if (idx < (RPB * 5) / 4) b4[idx] = xg[idx];
        }
    } else {
        for (int e = t; e < nrows * 5; e += 256) buf[e] = x[base * 5 + e];
    }
    __syncthreads();

    const float gmax = __uint_as_float(s_gmax);

    // ---- pull both rows' x into packed registers ----
    v2f X[5];
    {
        int rA = t, rB = 256 + t;
        int a = (rA < nrows) ? rA : 0;
        int b = (rB < nrows) ? rB : a;
#pragma unroll
        for (int k = 0; k < 5; ++k) X[k] = (v2f){ buf[a * 5 + k], buf[b * 5 + k] };
    }
    __syncthreads();

    // ---- bulk-zero the out region ----
    if (nrows == RPB) {
        v4f* b4 = (v4f*)buf;
        const v4f z = { 0.f, 0.f, 0.f, 0.f };
#pragma unroll
        for (int e = 0; e < 5; ++e) b4[e * 256 + t] = z;
    } else {
        for (int e = t; e < nrows * 10; e += 256) buf[e] = 0.0f;
    }
    __syncthreads();

    // ---- layer 1, both rows packed (v_pk_fma_f32) ----
    unsigned mA = 0u, mB = 0u;
#pragma unroll
    for (int j = 0; j < 32; ++j) {
        const float* w = W1 + j * 5;
        v2f h = X[0] * w[0];   // same expression form as R0-R4 -> same rounding
        h += X[1] * w[1];
        h += X[2] * w[2];
        h += X[3] * w[3];
        h += X[4] * w[4];
        if (h.x >= 2.0f) mA |= (1u << j);
        if (h.y >= 2.0f) mB |= (1u << j);
    }

    // ---- rare path: only rows with popc(m)*gmax >= 1.99 can fire L2 ----
#pragma unroll
    for (int c = 0; c < 2; ++c) {
        int lr = c * 256 + t;
        if (lr >= nrows) continue;
        unsigned m = c ? mB : mA;
        float bound = (float)__popc(m) * gmax;
        if (bound >= 1.99f) {
            float h[32];
#pragma unroll
            for (int j = 0; j < 32; ++j) h[j] = 0.0f;
            unsigned mm = m;           // ascending set-bit order == reference order
            while (mm) {
                int i = __ffs(mm) - 1;
                mm &= mm - 1;
                const float* wr = &w2t[i * 36];
#pragma unroll
                for (int j = 0; j < 32; ++j) h[j] += wr[j];
            }
            unsigned m2 = 0u;
#pragma unroll
            for (int j = 0; j < 32; ++j)
                if (h[j] >= 2.0f) m2 |= (1u << j);

            if (m2) {  // O(100) rows device-wide: exact layers 3+4
                unsigned m3 = 0u;
#pragma unroll
                for (int j = 0; j < 16; ++j) {
                    float g = 0.0f;
#pragma unroll
                    for (int i = 0; i < 32; ++i)
                        if ((m2 >> i) & 1u) g += W3[j * 32 + i];
                    if (g >= 2.0f) m3 |= (1u << j);
                }
                float o[10];
#pragma unroll
                for (int j = 0; j < 10; ++j) {
                    float g = 0.0f;
#pragma unroll
                    for (int i = 0; i < 16; ++i)
                        if ((m3 >> i) & 1u) g += W4[j * 16 + i];
                    o[j] = (g >= 2.0f) ? 1.0f : 0.0f;
                }
                v2f* bp = (v2f*)&buf[lr * 10];   // lr*10 even -> 8B aligned
#pragma unroll
                for (int q = 0; q < 5; ++q) bp[q] = (v2f){ o[2 * q], o[2 * q + 1] };
            }
        }
    }
    __syncthreads();

    // ---- coalesced nontemporal flush ----
    if (nrows == RPB) {
        v4f* og = (v4f*)(out + base * 10);
        const v4f* b4 = (const v4f*)buf;
#pragma unroll
        for (int e = 0; e < 5; ++e) {
            int idx = e * 256 + t;
            __builtin_nontemporal_store(b4[idx], &og[idx]);
        }
    } else {
        for (int e = t; e < nrows * 10; e += 256) out[base * 10 + e] = buf[e];
    }
}

extern "C" void kernel_launch(void* const* d_in, const int* in_sizes, int n_in,
                              void* d_out, int out_size, void* d_ws, size_t ws_size,
                              hipStream_t stream) {
    const float* x  = (const float*)d_in[0];
    const float* W1 = (const float*)d_in[1];
    const float* W2 = (const float*)d_in[2];
    const float* W3 = (const float*)d_in[3];
    const float* W4 = (const float*)d_in[4];
    float* out = (float*)d_out;

    int B = in_sizes[0] / 5;
    int grid = (B + RPB - 1) / RPB;
    snn_fused<<<grid, 256, 0, stream>>>(x, W1, W2, W3, W4, out, B);
}

// Round 7
// 145.405 us; speedup vs baseline: 1.1216x; 1.1216x over previous
//
#include <hip/hip_runtime.h>

// SNN forward, fused single-pass, R6.
//
// spike(h) = (h >= 2.0f)   (h/TAU >= 1 <=> h >= 2, exact in IEEE)
//
// Model (R2/R4/R5 counters): latency-bound, dur ~ 1/occupancy, with a VALU
// floor from (a) L1 math and (b) the sparse-L2 body running in EVERY wave.
// R6: 1 row/thread, 19.5KB LDS (8 blocks/CU), 2 barriers, and the sparse
// body gated by popc(m1)*gmax >= 1.99 (P(lane)~0.6% -> only ~32% of waves
// execute it via s_cbranch_execz; conservative bound -> exact).
// Conditional adds in ascending index order are bit-exact vs the reference
// fma chain (absmax 0.0, verified R1-R5).

typedef float v4f __attribute__((ext_vector_type(4)));

#define RPB 256   // rows per block, 1 per thread

__global__ __launch_bounds__(256) void snn_fused(
    const float* __restrict__ x,
    const float* __restrict__ W1,   // [32,5]
    const float* __restrict__ W2,   // [32,32]
    const float* __restrict__ W3,   // [16,32]
    const float* __restrict__ W4,   // [10,16]
    float* __restrict__ out,        // [B,10]
    int B)
{
    __shared__ __align__(16) float xs[RPB * 5];    // 5 KB x-stage
    __shared__ __align__(16) float os[RPB * 10];   // 10 KB out-stage
    __shared__ float w2t[32 * 36];                 // 4.5 KB W2^T, 144B rows
    __shared__ float red[4];                       // per-wave gmax

    const int t = threadIdx.x;
    const long base = (long)blockIdx.x * RPB;
    const int nrows = (int)min((long)RPB, (long)B - base);

    // ---- stage W2^T, tracking max positive entry (wave-reduced, no atomics) ----
    float lmax = 0.0f;
#pragma unroll
    for (int e = t; e < 1024; e += 256) {
        int j = e >> 5, i = e & 31;
        float w = W2[e];
        w2t[i * 36 + j] = w;
        lmax = fmaxf(lmax, w);
    }
#pragma unroll
    for (int k = 1; k < 64; k <<= 1)
        lmax = fmaxf(lmax, __shfl_xor(lmax, k, 64));
    if ((t & 63) == 0) red[t >> 6] = lmax;

    // ---- coalesced x stage + bulk-zero out stage (independent, same phase) ----
    if (nrows == RPB) {
        const v4f* xg = (const v4f*)(x + base * 5);
        v4f* xs4 = (v4f*)xs;
#pragma unroll
        for (int e = 0; e < 2; ++e) {
            int idx = e * 256 + t;
            if (idx < (RPB * 5) / 4) xs4[idx] = xg[idx];
        }
    } else {
        for (int e = t; e < nrows * 5; e += 256) xs[e] = x[base * 5 + e];
    }
    {
        v4f* os4 = (v4f*)os;
        const v4f z = { 0.f, 0.f, 0.f, 0.f };
#pragma unroll
        for (int e = 0; e < 3; ++e) {
            int idx = e * 256 + t;
            if (idx < (RPB * 10) / 4) os4[idx] = z;
        }
    }
    __syncthreads();

    const float gmax = fmaxf(fmaxf(red[0], red[1]), fmaxf(red[2], red[3]));

    if (t < nrows) {
        const float* xp = &xs[t * 5];
        float x0 = xp[0], x1 = xp[1], x2 = xp[2], x3 = xp[3], x4 = xp[4];

        // ---- layer 1 (W1 wave-uniform -> scalar loads), exact ref op order ----
        unsigned m = 0u;
#pragma unroll
        for (int j = 0; j < 32; ++j) {
            const float* w = W1 + j * 5;
            float h = x0 * w[0];
            h += x1 * w[1];
            h += x2 * w[2];
            h += x3 * w[3];
            h += x4 * w[4];
            if (h >= 2.0f) m |= (1u << j);
        }

        // ---- gated sparse layer 2 (+rare L3/L4) ----
        // h2_j <= popc(m)*gmax*(1+3eps); popc*gmax < 1.99 -> provably no fire.
        if ((float)__popc(m) * gmax >= 1.99f) {
            v4f h4[8];
#pragma unroll
            for (int q = 0; q < 8; ++q) h4[q] = (v4f){0.f, 0.f, 0.f, 0.f};
            unsigned mm = m;               // ascending set-bit order == ref order
            while (mm) {
                int i = __ffs(mm) - 1;
                mm &= mm - 1;
                const v4f* wr = (const v4f*)&w2t[i * 36];
#pragma unroll
                for (int q = 0; q < 8; ++q) h4[q] += wr[q];
            }
            unsigned m2 = 0u;
#pragma unroll
            for (int q = 0; q < 8; ++q) {
#pragma unroll
                for (int r = 0; r < 4; ++r)
                    if (h4[q][r] >= 2.0f) m2 |= (1u << (q * 4 + r));
            }

            if (m2) {  // O(100) rows device-wide: exact layers 3+4
                unsigned m3 = 0u;
#pragma unroll
                for (int j = 0; j < 16; ++j) {
                    float g = 0.0f;
#pragma unroll
                    for (int i = 0; i < 32; ++i)
                        if ((m2 >> i) & 1u) g += W3[j * 32 + i];
                    if (g >= 2.0f) m3 |= (1u << j);
                }
#pragma unroll
                for (int j = 0; j < 10; ++j) {
                    float g = 0.0f;
#pragma unroll
                    for (int i = 0; i < 16; ++i)
                        if ((m3 >> i) & 1u) g += W4[j * 16 + i];
                    os[t * 10 + j] = (g >= 2.0f) ? 1.0f : 0.0f;
                }
            }
        }
    }
    __syncthreads();

    // ---- coalesced nontemporal flush: RPB*10 = 2560 floats = 640 v4f ----
    if (nrows == RPB) {
        v4f* og = (v4f*)(out + base * 10);
        const v4f* os4 = (const v4f*)os;
#pragma unroll
        for (int e = 0; e < 3; ++e) {
            int idx = e * 256 + t;
            if (idx < (RPB * 10) / 4)
                __builtin_nontemporal_store(os4[idx], &og[idx]);
        }
    } else {
        for (int e = t; e < nrows * 10; e += 256) out[base * 10 + e] = os[e];
    }
}

extern "C" void kernel_launch(void* const* d_in, const int* in_sizes, int n_in,
                              void* d_out, int out_size, void* d_ws, size_t ws_size,
                              hipStream_t stream) {
    const float* x  = (const float*)d_in[0];
    const float* W1 = (const float*)d_in[1];
    const float* W2 = (const float*)d_in[2];
    const float* W3 = (const float*)d_in[3];
    const float* W4 = (const float*)d_in[4];
    float* out = (float*)d_out;

    int B = in_sizes[0] / 5;
    int grid = (B + RPB - 1) / RPB;
    snn_fused<<<grid, 256, 0, stream>>>(x, W1, W2, W3, W4, out, B);
}